// Round 16
// baseline (129.502 us; speedup 1.0000x reference)
//
#include <hip/hip_runtime.h>
#include <hip/hip_bf16.h>

typedef __attribute__((ext_vector_type(4))) float f32x4;
typedef __attribute__((ext_vector_type(8))) __bf16 bf16x8;

#define NCTX 8192
#define DH 128
#define ROWE 4096                    /* floats between consecutive positions */
#define SC2 0.12751705766482797f     /* (1/sqrt(128)) * log2(e) */
#define KSTR 136                     /* bf16 row stride in staged buffers */
#define PSTR 40                      /* P lds row stride (shorts) */
#define OSTR 132                     /* O-bounce row stride (floats) */
#define QSTRIDE 17408                /* bytes per padded f32 Q buf (1088 x 16B granules) */
#define KVOFF (8*QSTRIDE)            /* block K/V bufs at 139264 */
#define LDS_TOTAL (KVOFF + 2*8704)   /* 156672 B */
#define VOFF_B 8704                  /* private V bf16 region in qcur */
#define OOFF_B 2560                  /* O bounce region in qcur */

__device__ __forceinline__ unsigned f2bf(float x) {
  union { float f; unsigned u; } un; un.f = x;
  return (un.u + 0x7FFFu + ((un.u >> 16) & 1u)) >> 16;   // RNE f32->bf16 bits
}
__device__ __forceinline__ unsigned pk2(float a, float b) {
  float2 t; t.x = a; t.y = b;
  union { __hip_bfloat162 h; unsigned u; } un;
  un.h = __float22bfloat162_rn(t);
  return un.u;
}
__device__ __forceinline__ bf16x8 mk8(f32x4 x, f32x4 y) {
  union { unsigned u[4]; bf16x8 f; } un;
  un.u[0] = pk2(x[0], x[1]); un.u[1] = pk2(x[2], x[3]);
  un.u[2] = pk2(y[0], y[1]); un.u[3] = pk2(y[2], y[3]);
  return un.f;
}

// Stage one 4096-float global row -> LDS bf16 [32][KSTR], fully coalesced.
__device__ __forceinline__ void stage_row(const float* __restrict__ src,
                                          unsigned short* dst, int lane) {
  const int jb = lane >> 5, d = 4 * (lane & 31);
#pragma unroll
  for (int half = 0; half < 2; ++half) {
    f32x4 x[8];
#pragma unroll
    for (int ch = 0; ch < 8; ++ch)
      x[ch] = *reinterpret_cast<const f32x4*>(src + 4*lane + 256*(half*8 + ch));
#pragma unroll
    for (int ch = 0; ch < 8; ++ch) {
      const int j = jb + 2*(half*8 + ch);
      uint2 wv;
      wv.x = pk2(x[ch][0], x[ch][1]);
      wv.y = pk2(x[ch][2], x[ch][3]);
      *reinterpret_cast<uint2*>(&dst[j*KSTR + d]) = wv;
    }
  }
}

// Async-DMA one Q row (4096 f32) into a padded-132 f32 LDS buffer.
// dest granule t = k*64+lane maps to (row=t/33, colgrp=t%33); source per-lane
// address pre-swizzled so linear DMA dest == padded layout (pad/tail clamped).
__device__ __forceinline__ void dma_q(const float* __restrict__ qsrc,
                                      char* dst, int lane) {
#pragma unroll
  for (int k = 0; k < 17; ++k) {
    const int t = (k << 6) + lane;
    int row = (t * 993) >> 15;        // exact t/33 for t < 1088
    int cg  = t - row * 33;
    row = min(row, 31); cg = min(cg, 31);
    __builtin_amdgcn_global_load_lds(
        reinterpret_cast<const unsigned int*>(qsrc + row*128 + cg*4),
        reinterpret_cast<unsigned int*>(dst + (k << 10)), 16, 0, 0);
  }
}

// One wave : 4 consecutive positions, Q double-buffered via global_load_lds.
// Counted vmcnt(16) at iteration head leaves store-acks in flight; next Q DMA
// issued before compute -> ~16KB continuously outstanding per wave.
__global__ __launch_bounds__(256, 1) void hda(
    const float* __restrict__ q, const float* __restrict__ kg,
    const float* __restrict__ v, float* __restrict__ out)
{
  extern __shared__ __align__(16) char lds[];

  const int tid  = threadIdx.x;
  const int w    = tid >> 6;
  const int lane = tid & 63;
  const int c = lane & 15;
  const int g = lane >> 4;
  const int jb = lane >> 5, dcol = 4 * (lane & 31);

  const int p0 = (blockIdx.x * 4 + w) * 4;   // first position of this wave
  const int b  = p0 >> 13;
  const int s0 = p0 & (NCTX - 1);
  const bool shared_kv = (s0 >= 2048);       // block-uniform (16 | 2048)

  const float* qb_ = q  + (size_t)b * NCTX * ROWE;
  const float* kb_ = kg + (size_t)b * NCTX * ROWE;
  const float* vb_ = v  + (size_t)b * NCTX * ROWE;
  float*       ob_ = out + (size_t)b * NCTX * ROWE;

  char* qb0 = lds + w * 2 * QSTRIDE;
  char* qb1 = qb0 + QSTRIDE;
  unsigned short* kvK = reinterpret_cast<unsigned short*>(lds + KVOFF);
  unsigned short* kvV = kvK + 32 * KSTR;

  // ---- shared blocks: coop one-time staging of K/V row 8191 (L2-hot)
  if (shared_kv) {
    const float* kr8 = kb_ + (size_t)(NCTX - 1) * ROWE;
    const float* vr8 = vb_ + (size_t)(NCTX - 1) * ROWE;
    const int d0 = 4 * (tid & 31), jj = tid >> 5;
#pragma unroll
    for (int ch = 0; ch < 4; ++ch) {
      const int fo = 4*tid + 1024*ch;
      const int j  = jj + 8*ch;
      f32x4 xk = *reinterpret_cast<const f32x4*>(kr8 + fo);
      f32x4 xv = *reinterpret_cast<const f32x4*>(vr8 + fo);
      uint2 wk, wv2;
      wk.x  = pk2(xk[0], xk[1]); wk.y  = pk2(xk[2], xk[3]);
      wv2.x = pk2(xv[0], xv[1]); wv2.y = pk2(xv[2], xv[3]);
      *reinterpret_cast<uint2*>(&kvK[j*KSTR + d0]) = wk;
      *reinterpret_cast<uint2*>(&kvV[j*KSTR + d0]) = wv2;
    }
    __syncthreads();
  }

  // ---- prologue: DMA Q(p0) into buffer 0
  dma_q(qb_ + (size_t)s0 * ROWE, qb0, lane);

#pragma unroll 1
  for (int i = 0; i < 4; ++i) {
    const int s = s0 + i;
    char* qcur = (i & 1) ? qb1 : qb0;
    char* qnxt = (i & 1) ? qb0 : qb1;

    // wait current Q DMA (older) while leaving prev stores (younger) in flight
    if (i == 0) asm volatile("s_waitcnt vmcnt(0)" ::: "memory");
    else        asm volatile("s_waitcnt vmcnt(16)" ::: "memory");
    __builtin_amdgcn_sched_barrier(0);

    // ---- Q A-frags directly from padded f32 LDS (b128 floor-rate reads)
    bf16x8 qa[2][4];
#pragma unroll
    for (int t = 0; t < 2; ++t)
#pragma unroll
      for (int ks = 0; ks < 4; ++ks) {
        const int gr = (t*16 + c)*33 + ks*8 + 2*g;
        f32x4 x = *reinterpret_cast<const f32x4*>(qcur + gr*16);
        f32x4 y = *reinterpret_cast<const f32x4*>(qcur + gr*16 + 16);
        qa[t][ks] = mk8(x, y);
      }

    // ---- issue next position's Q DMA (fire-and-forget, hides under compute)
    if (i < 3)
      dma_q(qb_ + (size_t)(s + 1) * ROWE, qnxt, lane);

    // ---- K frags
    unsigned short* sbK = reinterpret_cast<unsigned short*>(qcur);
    const unsigned short* kb = shared_kv ? kvK : sbK;
    if (!shared_kv)
      stage_row(kb_ + (size_t)(4*s) * ROWE, sbK, lane);
    bf16x8 kf[2][4];
#pragma unroll
    for (int t = 0; t < 2; ++t)
#pragma unroll
      for (int ks = 0; ks < 4; ++ks)
        kf[t][ks] = *reinterpret_cast<const bf16x8*>(&kb[(t*16 + c)*KSTR + ks*32 + g*8]);

    // ---- private: issue V half 1 to regs (T14), hides under QK-MFMA
    const float* vsrc = vb_ + (size_t)(4*s) * ROWE;
    unsigned short* sbV = reinterpret_cast<unsigned short*>(qcur + VOFF_B);
    const unsigned short* vbuf = shared_kv ? kvV : sbV;
    f32x4 vx[8];
    if (!shared_kv) {
#pragma unroll
      for (int ch = 0; ch < 8; ++ch)
        vx[ch] = *reinterpret_cast<const f32x4*>(vsrc + 4*lane + 256*ch);
      __builtin_amdgcn_sched_barrier(0);
    }

    // ---- S = Q K^T
    f32x4 S[2][2];
#pragma unroll
    for (int it = 0; it < 2; ++it)
#pragma unroll
      for (int jt = 0; jt < 2; ++jt) {
        f32x4 acc = (f32x4)0.0f;
#pragma unroll
        for (int ks = 0; ks < 4; ++ks)
          acc = __builtin_amdgcn_mfma_f32_16x16x32_bf16(qa[it][ks], kf[jt][ks], acc, 0, 0, 0);
        S[it][jt] = acc;
      }

    // ---- private: write V half 1, issue half 2
    if (!shared_kv) {
#pragma unroll
      for (int ch = 0; ch < 8; ++ch) {
        uint2 wv;
        wv.x = pk2(vx[ch][0], vx[ch][1]);
        wv.y = pk2(vx[ch][2], vx[ch][3]);
        *reinterpret_cast<uint2*>(&sbV[(jb + 2*ch)*KSTR + dcol]) = wv;
      }
#pragma unroll
      for (int ch = 0; ch < 8; ++ch)
        vx[ch] = *reinterpret_cast<const f32x4*>(vsrc + 4*lane + 256*(8 + ch));
      __builtin_amdgcn_sched_barrier(0);
    }

    // ---- softmax over 32 cols
    float pp[2][2][4], inv[2][4];
#pragma unroll
    for (int it = 0; it < 2; ++it) {
      float ls[4] = {0.f, 0.f, 0.f, 0.f};
#pragma unroll
      for (int jt = 0; jt < 2; ++jt)
#pragma unroll
        for (int rr = 0; rr < 4; ++rr) {
          float e = exp2f(S[it][jt][rr] * SC2);
          pp[it][jt][rr] = e;
          ls[rr] += e;
        }
#pragma unroll
      for (int m = 1; m <= 8; m <<= 1)
#pragma unroll
        for (int rr = 0; rr < 4; ++rr)
          ls[rr] += __shfl_xor(ls[rr], m);
#pragma unroll
      for (int rr = 0; rr < 4; ++rr) inv[it][rr] = 1.0f / ls[rr];
    }

    // ---- private: write V half 2
    if (!shared_kv) {
#pragma unroll
      for (int ch = 0; ch < 8; ++ch) {
        uint2 wv;
        wv.x = pk2(vx[ch][0], vx[ch][1]);
        wv.y = pk2(vx[ch][2], vx[ch][3]);
        *reinterpret_cast<uint2*>(&sbV[(jb + 2*(8 + ch))*KSTR + dcol]) = wv;
      }
    }

    // ---- V B-frags via u16 gather
    bf16x8 va[8];
#pragma unroll
    for (int dt = 0; dt < 8; ++dt) {
      unsigned t0 = vbuf[(g*8 + 0)*KSTR + dt*16 + c];
      unsigned t1 = vbuf[(g*8 + 1)*KSTR + dt*16 + c];
      unsigned t2 = vbuf[(g*8 + 2)*KSTR + dt*16 + c];
      unsigned t3 = vbuf[(g*8 + 3)*KSTR + dt*16 + c];
      unsigned t4 = vbuf[(g*8 + 4)*KSTR + dt*16 + c];
      unsigned t5 = vbuf[(g*8 + 5)*KSTR + dt*16 + c];
      unsigned t6 = vbuf[(g*8 + 6)*KSTR + dt*16 + c];
      unsigned t7 = vbuf[(g*8 + 7)*KSTR + dt*16 + c];
      union { unsigned u[4]; bf16x8 f; } un;
      un.u[0] = t0 | (t1 << 16); un.u[1] = t2 | (t3 << 16);
      un.u[2] = t4 | (t5 << 16); un.u[3] = t6 | (t7 << 16);
      va[dt] = un.f;
    }

    // ---- normalized P -> qcur[0,2560), read back as A-frags
    unsigned short* sbP = reinterpret_cast<unsigned short*>(qcur);
#pragma unroll
    for (int it = 0; it < 2; ++it)
#pragma unroll
      for (int jt = 0; jt < 2; ++jt)
#pragma unroll
        for (int rr = 0; rr < 4; ++rr)
          sbP[(it*16 + g*4 + rr)*PSTR + jt*16 + c] =
              (unsigned short)f2bf(pp[it][jt][rr] * inv[it][rr]);

    bf16x8 pa[2];
    pa[0] = *reinterpret_cast<const bf16x8*>(&sbP[c*PSTR + g*8]);
    pa[1] = *reinterpret_cast<const bf16x8*>(&sbP[(16 + c)*PSTR + g*8]);

    // ---- O^T = V^T P^T ; LDS bounce -> full-line NT stores
    float* op = ob_ + (size_t)s * ROWE;
    float* ob = reinterpret_cast<float*>(qcur + OOFF_B);
#pragma unroll
    for (int it = 0; it < 2; ++it) {
      f32x4 o[8];
#pragma unroll
      for (int dt = 0; dt < 8; ++dt)
        o[dt] = __builtin_amdgcn_mfma_f32_16x16x32_bf16(va[dt], pa[it], (f32x4)0.0f, 0, 0, 0);
#pragma unroll
      for (int dt = 0; dt < 8; ++dt)
        *reinterpret_cast<f32x4*>(&ob[c*OSTR + dt*16 + g*4]) = o[dt];
#pragma unroll
      for (int ch = 0; ch < 8; ++ch) {
        const int flat = 4*lane + 256*ch;
        const int row = flat >> 7, col = flat & 127;
        f32x4 y = *reinterpret_cast<const f32x4*>(&ob[row*OSTR + col]);
        __builtin_nontemporal_store(y, reinterpret_cast<f32x4*>(op + it*2048 + flat));
      }
    }
  }
}

extern "C" void kernel_launch(void* const* d_in, const int* in_sizes, int n_in,
                              void* d_out, int out_size, void* d_ws, size_t ws_size,
                              hipStream_t stream) {
  const float* q = (const float*)d_in[0];
  const float* k = (const float*)d_in[1];
  const float* v = (const float*)d_in[2];
  float* o = (float*)d_out;
  // >64KB dynamic LDS opt-in (idempotent host-side call; capture-safe)
  hipFuncSetAttribute(reinterpret_cast<const void*>(hda),
                      hipFuncAttributeMaxDynamicSharedMemorySize, LDS_TOTAL);
  // 16384 positions / (4 waves x 4 pos) = 1024 blocks; 156672 B LDS -> 1 block/CU
  hda<<<dim3(1024, 1, 1), dim3(256, 1, 1), LDS_TOTAL, stream>>>(q, k, v, o);
}

// Round 17
// 113.143 us; speedup vs baseline: 1.1446x; 1.1446x over previous
//
#include <hip/hip_runtime.h>
#include <hip/hip_bf16.h>

typedef __attribute__((ext_vector_type(4))) float f32x4;
typedef __attribute__((ext_vector_type(8))) __bf16 bf16x8;

#define NCTX 8192
#define DH 128
#define ROWE 4096                    /* floats between consecutive positions */
#define SC2 0.12751705766482797f     /* (1/sqrt(128)) * log2(e) */
#define KSTR 136                     /* bf16 row stride in staged buffers */
#define PSTR 40                      /* P lds row stride (shorts) */
#define OSTR 132                     /* O-bounce row stride (floats) */
#define BUFS (32*KSTR)               /* shorts per 8.5KB buffer */

__device__ __forceinline__ unsigned f2bf(float x) {
  union { float f; unsigned u; } un; un.f = x;
  return (un.u + 0x7FFFu + ((un.u >> 16) & 1u)) >> 16;   // RNE f32->bf16 bits
}
// pair convert via v_cvt_pk_bf16_f32
__device__ __forceinline__ unsigned pk2(float a, float b) {
  float2 t; t.x = a; t.y = b;
  union { __hip_bfloat162 h; unsigned u; } un;
  un.h = __float22bfloat162_rn(t);
  return un.u;
}

// Stage one 4096-float global row -> LDS bf16 [32][KSTR], fully coalesced.
// NT=true: nontemporal loads (stream-once data, don't pollute L2/L3).
template<bool NT>
__device__ __forceinline__ void stage_row(const float* __restrict__ src,
                                          unsigned short* dst, int lane) {
  const int jb = lane >> 5, d = 4 * (lane & 31);
#pragma unroll
  for (int half = 0; half < 2; ++half) {
    f32x4 x[8];
#pragma unroll
    for (int ch = 0; ch < 8; ++ch) {
      const f32x4* p = reinterpret_cast<const f32x4*>(src + 4*lane + 256*(half*8 + ch));
      x[ch] = NT ? __builtin_nontemporal_load(p) : *p;
    }
#pragma unroll
    for (int ch = 0; ch < 8; ++ch) {
      const int j = jb + 2*(half*8 + ch);       // head row 0..31
      uint2 wv;
      wv.x = pk2(x[ch][0], x[ch][1]);
      wv.y = pk2(x[ch][2], x[ch][3]);
      *reinterpret_cast<uint2*>(&dst[j*KSTR + d]) = wv;
    }
  }
}

// One wave per position: 32(heads) x 32(heads) attention, d=128.
// Private path: Q -> K staged serially through sb; V issued early to regs
// (two 8x float4 halves) and written to sb under the QK-MFMA / softmax.
__global__ __launch_bounds__(256, 3) void hda(
    const float* __restrict__ q, const float* __restrict__ kg,
    const float* __restrict__ v, float* __restrict__ out)
{
  extern __shared__ __align__(16) unsigned short lds[];   // 6 bufs of BUFS shorts

  const int tid  = threadIdx.x;
  const int w    = tid >> 6;
  const int lane = tid & 63;
  const int c = lane & 15;    // frag row/col index
  const int g = lane >> 4;    // lane group 0..3
  const int jb = lane >> 5, dcol = 4 * (lane & 31);   // staging lane map

  const int pos = blockIdx.x * 4 + w;     // 0..16383
  const int b = pos >> 13;
  const int s = pos & (NCTX - 1);
  const int s0 = (blockIdx.x * 4) & (NCTX - 1);
  const bool shared_kv = (s0 >= 2048);    // then r = 8191 for the whole block

  const float* qb_ = q  + (size_t)b * NCTX * ROWE;
  const float* kb_ = kg + (size_t)b * NCTX * ROWE;
  const float* vb_ = v  + (size_t)b * NCTX * ROWE;
  float*       op  = out + ((size_t)b * NCTX + s) * ROWE;

  unsigned short* sb = lds + w * BUFS;    // per-wave buf (Q -> K -> V -> P -> O)
  const unsigned short* kbuf = shared_kv ? (lds + 4*BUFS) : sb;
  const unsigned short* vbuf = shared_kv ? (lds + 5*BUFS) : sb;

  // ---- shared-KV blocks: cooperative one-time staging of K/V row 8191 (hot)
  if (shared_kv) {
    const float* kr8 = kb_ + (size_t)(NCTX - 1) * ROWE;
    const float* vr8 = vb_ + (size_t)(NCTX - 1) * ROWE;
    const int d = 4 * (tid & 31), jj = tid >> 5;
#pragma unroll
    for (int ch = 0; ch < 4; ++ch) {
      const int fo = 4*tid + 1024*ch;
      const int j  = jj + 8*ch;
      f32x4 xk = *reinterpret_cast<const f32x4*>(kr8 + fo);
      f32x4 xv = *reinterpret_cast<const f32x4*>(vr8 + fo);
      uint2 wk, wv2;
      wk.x  = pk2(xk[0], xk[1]); wk.y  = pk2(xk[2], xk[3]);
      wv2.x = pk2(xv[0], xv[1]); wv2.y = pk2(xv[2], xv[3]);
      *reinterpret_cast<uint2*>(&lds[4*BUFS + j*KSTR + d]) = wk;
      *reinterpret_cast<uint2*>(&lds[5*BUFS + j*KSTR + d]) = wv2;
    }
    __syncthreads();
  }

  // ---- Q: stage own row (nontemporal: read-once stream) -> frags
  stage_row<true>(qb_ + (size_t)s * ROWE, sb, lane);
  bf16x8 qa[2][4];
#pragma unroll
  for (int t = 0; t < 2; ++t)
#pragma unroll
    for (int ks = 0; ks < 4; ++ks)
      qa[t][ks] = *reinterpret_cast<const bf16x8*>(&sb[(t*16 + c)*KSTR + ks*32 + g*8]);

  // ---- K: shared blocks read staged row 8191; private blocks stage r = 4s
  const float* vsrc = vb_ + (size_t)(min(4*s, NCTX-1)) * ROWE;  // private V source
  if (!shared_kv)
    stage_row<false>(kb_ + (size_t)(4*s) * ROWE, sb, lane);
  bf16x8 kf[2][4];
#pragma unroll
  for (int t = 0; t < 2; ++t)
#pragma unroll
    for (int ks = 0; ks < 4; ++ks)
      kf[t][ks] = *reinterpret_cast<const bf16x8*>(&kbuf[(t*16 + c)*KSTR + ks*32 + g*8]);

  // ---- private: issue V half 1 (rows 0..15) to regs; hides under QK-MFMA
  f32x4 vx[8];
  if (!shared_kv) {
#pragma unroll
    for (int ch = 0; ch < 8; ++ch)
      vx[ch] = *reinterpret_cast<const f32x4*>(vsrc + 4*lane + 256*ch);
    __builtin_amdgcn_sched_barrier(0);
  }

  // ---- S = Q K^T over heads: 4 16x16 tiles, K-dim 128
  f32x4 S[2][2];
#pragma unroll
  for (int it = 0; it < 2; ++it)
#pragma unroll
    for (int jt = 0; jt < 2; ++jt) {
      f32x4 acc = (f32x4)0.0f;
#pragma unroll
      for (int ks = 0; ks < 4; ++ks)
        acc = __builtin_amdgcn_mfma_f32_16x16x32_bf16(qa[it][ks], kf[jt][ks], acc, 0, 0, 0);
      S[it][jt] = acc;
    }

  // ---- private: write V half 1 into sb (K frags consumed), issue half 2
  if (!shared_kv) {
#pragma unroll
    for (int ch = 0; ch < 8; ++ch) {
      uint2 wv;
      wv.x = pk2(vx[ch][0], vx[ch][1]);
      wv.y = pk2(vx[ch][2], vx[ch][3]);
      *reinterpret_cast<uint2*>(&sb[(jb + 2*ch)*KSTR + dcol]) = wv;
    }
#pragma unroll
    for (int ch = 0; ch < 8; ++ch)
      vx[ch] = *reinterpret_cast<const f32x4*>(vsrc + 4*lane + 256*(8 + ch));
    __builtin_amdgcn_sched_barrier(0);
  }

  // D-layout: S[it][jt][rr] = S_full[it*16+g*4+rr][jt*16+c]
  // ---- softmax over 32 cols (no max-sub: scores ~N(0,1), exp2 arg small)
  float p[2][2][4], inv[2][4];
#pragma unroll
  for (int it = 0; it < 2; ++it) {
    float ls[4] = {0.f, 0.f, 0.f, 0.f};
#pragma unroll
    for (int jt = 0; jt < 2; ++jt)
#pragma unroll
      for (int rr = 0; rr < 4; ++rr) {
        float e = exp2f(S[it][jt][rr] * SC2);
        p[it][jt][rr] = e;
        ls[rr] += e;
      }
#pragma unroll
    for (int m = 1; m <= 8; m <<= 1)
#pragma unroll
      for (int rr = 0; rr < 4; ++rr)
        ls[rr] += __shfl_xor(ls[rr], m);
#pragma unroll
    for (int rr = 0; rr < 4; ++rr) inv[it][rr] = 1.0f / ls[rr];
  }

  // ---- private: write V half 2 (rows 16..31) into sb
  if (!shared_kv) {
#pragma unroll
    for (int ch = 0; ch < 8; ++ch) {
      uint2 wv;
      wv.x = pk2(vx[ch][0], vx[ch][1]);
      wv.y = pk2(vx[ch][2], vx[ch][3]);
      *reinterpret_cast<uint2*>(&sb[(jb + 2*(8 + ch))*KSTR + dcol]) = wv;
    }
  }

  // ---- V B-frags via LDS u16 gather (before P overwrites sb)
  bf16x8 va[8];
#pragma unroll
  for (int dt = 0; dt < 8; ++dt) {
    unsigned t0 = vbuf[(g*8 + 0)*KSTR + dt*16 + c];
    unsigned t1 = vbuf[(g*8 + 1)*KSTR + dt*16 + c];
    unsigned t2 = vbuf[(g*8 + 2)*KSTR + dt*16 + c];
    unsigned t3 = vbuf[(g*8 + 3)*KSTR + dt*16 + c];
    unsigned t4 = vbuf[(g*8 + 4)*KSTR + dt*16 + c];
    unsigned t5 = vbuf[(g*8 + 5)*KSTR + dt*16 + c];
    unsigned t6 = vbuf[(g*8 + 6)*KSTR + dt*16 + c];
    unsigned t7 = vbuf[(g*8 + 7)*KSTR + dt*16 + c];
    union { unsigned u[4]; bf16x8 f; } un;
    un.u[0] = t0 | (t1 << 16); un.u[1] = t2 | (t3 << 16);
    un.u[2] = t4 | (t5 << 16); un.u[3] = t6 | (t7 << 16);
    va[dt] = un.f;
  }

  // ---- normalized P -> sb (row-major [i][j]), read back as A-frags
#pragma unroll
  for (int it = 0; it < 2; ++it)
#pragma unroll
    for (int jt = 0; jt < 2; ++jt)
#pragma unroll
      for (int rr = 0; rr < 4; ++rr)
        sb[(it*16 + g*4 + rr)*PSTR + jt*16 + c] =
            (unsigned short)f2bf(p[it][jt][rr] * inv[it][rr]);

  bf16x8 pa[2];   // lane holds P[it*16+c][g*8..+7]
  pa[0] = *reinterpret_cast<const bf16x8*>(&sb[c*PSTR + g*8]);
  pa[1] = *reinterpret_cast<const bf16x8*>(&sb[(16 + c)*PSTR + g*8]);

  // ---- O^T = V^T P^T per it-half; bounce through LDS for coalesced nt stores
  float* ob = reinterpret_cast<float*>(sb);    // P already consumed
#pragma unroll
  for (int it = 0; it < 2; ++it) {
    f32x4 o[8];
#pragma unroll
    for (int dt = 0; dt < 8; ++dt)
      o[dt] = __builtin_amdgcn_mfma_f32_16x16x32_bf16(va[dt], pa[it], (f32x4)0.0f, 0, 0, 0);
    // D[g*4+rr][c] = O[it*16+c][dt*16+g*4+rr] -> LDS row c (head), col d
#pragma unroll
    for (int dt = 0; dt < 8; ++dt)
      *reinterpret_cast<f32x4*>(&ob[c*OSTR + dt*16 + g*4]) = o[dt];
    // coalesced flush: 8 full-line nontemporal dwordx4 stores (write-once)
#pragma unroll
    for (int ch = 0; ch < 8; ++ch) {
      const int flat = 4*lane + 256*ch;        // 0..2047
      const int row = flat >> 7, col = flat & 127;
      f32x4 y = *reinterpret_cast<const f32x4*>(&ob[row*OSTR + col]);
      __builtin_nontemporal_store(y, reinterpret_cast<f32x4*>(op + it*2048 + flat));
    }
  }
}

extern "C" void kernel_launch(void* const* d_in, const int* in_sizes, int n_in,
                              void* d_out, int out_size, void* d_ws, size_t ws_size,
                              hipStream_t stream) {
  const float* q = (const float*)d_in[0];
  const float* k = (const float*)d_in[1];
  const float* v = (const float*)d_in[2];
  float* o = (float*)d_out;
  // 16384 positions (b=2 x s=8192), 4 waves/block -> 4096 blocks; 52224 B LDS
  hda<<<dim3(4096, 1, 1), dim3(256, 1, 1), 6 * BUFS * 2, stream>>>(q, k, v, o);
}